// Round 1
// baseline (735.104 us; speedup 1.0000x reference)
//
#include <hip/hip_runtime.h>
#include <math.h>

#define B_DIM 4
#define T_DIM 256
#define C_DIM 256
#define NB 8
#define BS 32
#define LAM 0.01f

__global__ void afno_init(const float* __restrict__ x, float* __restrict__ out, int n) {
    int i = blockIdx.x * blockDim.x + threadIdx.x;
    if (i < n) out[i] = x[i];
}

// One workgroup per (group g, batch b, block n, chunk of 8 frequencies).
// Thread (pl, li): pl = freq-within-chunk, li = channel-in-block (role: i for
// forward DFT, o for layer1 output, i for layer2 output / final channel).
__global__ __launch_bounds__(256, 2)
void afno_main(const float* __restrict__ x,
               const float* __restrict__ w1,
               const float* __restrict__ b1,
               const float* __restrict__ w2,
               const float* __restrict__ b2,
               float* __restrict__ out) {
    const int gP[7]  = {8, 16, 32, 64, 128, 256, 512};
    const int gT0[7] = {0, 7, 15, 31, 63, 127, 255};
    const int gT1[7] = {6, 14, 30, 62, 126, 254, 255};
    const int gOff[8] = {0, 32, 96, 224, 480, 992, 2016, 4064}; // cum. 4*P wgs per group

    int bid = blockIdx.x;
    int g = 0;
    #pragma unroll
    for (int k = 1; k < 7; ++k) if (bid >= gOff[k]) g = k;
    int r = bid - gOff[g];
    int chunk = r >> 5;      // [0, P/8)
    int bn    = r & 31;      // [0, 32)
    int b = bn >> 3;         // [0, 4)
    int n = bn & 7;          // [0, 8)
    int P  = gP[g];
    int t0 = gT0[g];
    int t1 = gT1[g];
    int pmask = P - 1;
    float invSqrtP = rsqrtf((float)P);
    float angStep = 6.28318530717958647692f / (float)P;

    int tid = threadIdx.x;
    int pl = tid >> 5;       // 0..7
    int li = tid & 31;       // 0..31
    int p  = chunk * 8 + pl; // frequency index

    __shared__ float xs[256 * 32];        // x[b, s, n*32+i], s = 0..t1   (32 KB)
    __shared__ float Xre_l[8 * 32];
    __shared__ float Xim_l[8 * 32];
    __shared__ float o1r_l[8 * 32];
    __shared__ float o1i_l[8 * 32];
    __shared__ float part[8 * 32];

    // stage x block into LDS (coalesced)
    for (int idx = tid; idx < (t1 + 1) * 32; idx += 256) {
        int s = idx >> 5, i = idx & 31;
        xs[idx] = x[(b * T_DIM + s) * C_DIM + n * 32 + i];
    }

    // weights into registers:
    //  layer1: output channel o = li needs w1[*][n][i][li], i = 0..31
    //  layer2: output channel i = li needs w2[*][n][o][li], o = 0..31
    float w10c[32], w11c[32], w20r[32], w21r[32];
    #pragma unroll
    for (int i = 0; i < 32; ++i) {
        w10c[i] = w1[((0 * NB + n) * BS + i) * BS + li];
        w11c[i] = w1[((1 * NB + n) * BS + i) * BS + li];
        w20r[i] = w2[((0 * NB + n) * BS + i) * BS + li];
        w21r[i] = w2[((1 * NB + n) * BS + i) * BS + li];
    }
    float b1r_ = b1[(0 * NB + n) * BS + li];
    float b1i_ = b1[(1 * NB + n) * BS + li];
    float b2r_ = b2[(0 * NB + n) * BS + li];
    float b2i_ = b2[(1 * NB + n) * BS + li];

    __syncthreads();

    float Xre = 0.f, Xim = 0.f;

    for (int s = 0; s <= t1; ++s) {
        // incremental prefix DFT: X[p] += e^{-2*pi*i*p*s/P} * x[s]
        float xv = xs[s * 32 + li];
        int m = (p * s) & pmask;
        float sn, cs;
        __sincosf(angStep * (float)m, &sn, &cs);
        Xre = fmaf(xv, cs, Xre);
        Xim = fmaf(xv, -sn, Xim);

        if (s >= t0) {
            int t = s;
            // snapshot normalized X to LDS
            Xre_l[pl * 32 + li] = Xre * invSqrtP;
            Xim_l[pl * 32 + li] = Xim * invSqrtP;
            __syncthreads();

            // layer 1: o1[o=li] = relu( sum_i re*w10 - im*w11 + b1r , ... )
            float a1r = b1r_, a1i = b1i_;
            const float4* xr4 = (const float4*)(Xre_l + pl * 32);
            const float4* xi4 = (const float4*)(Xim_l + pl * 32);
            #pragma unroll
            for (int i4 = 0; i4 < 8; ++i4) {
                float4 vr = xr4[i4];
                float4 vi = xi4[i4];
                a1r += vr.x * w10c[4 * i4 + 0] - vi.x * w11c[4 * i4 + 0];
                a1i += vi.x * w10c[4 * i4 + 0] + vr.x * w11c[4 * i4 + 0];
                a1r += vr.y * w10c[4 * i4 + 1] - vi.y * w11c[4 * i4 + 1];
                a1i += vi.y * w10c[4 * i4 + 1] + vr.y * w11c[4 * i4 + 1];
                a1r += vr.z * w10c[4 * i4 + 2] - vi.z * w11c[4 * i4 + 2];
                a1i += vi.z * w10c[4 * i4 + 2] + vr.z * w11c[4 * i4 + 2];
                a1r += vr.w * w10c[4 * i4 + 3] - vi.w * w11c[4 * i4 + 3];
                a1i += vi.w * w10c[4 * i4 + 3] + vr.w * w11c[4 * i4 + 3];
            }
            a1r = fmaxf(a1r, 0.f);
            a1i = fmaxf(a1i, 0.f);
            o1r_l[pl * 32 + li] = a1r;
            o1i_l[pl * 32 + li] = a1i;
            __syncthreads();

            // layer 2: o2[i=li] = sum_o o1r*w20 - o1i*w21 + b2r , ...
            float a2r = b2r_, a2i = b2i_;
            const float4* or4 = (const float4*)(o1r_l + pl * 32);
            const float4* oi4 = (const float4*)(o1i_l + pl * 32);
            #pragma unroll
            for (int o4 = 0; o4 < 8; ++o4) {
                float4 vr = or4[o4];
                float4 vi = oi4[o4];
                a2r += vr.x * w20r[4 * o4 + 0] - vi.x * w21r[4 * o4 + 0];
                a2i += vi.x * w20r[4 * o4 + 0] + vr.x * w21r[4 * o4 + 0];
                a2r += vr.y * w20r[4 * o4 + 1] - vi.y * w21r[4 * o4 + 1];
                a2i += vi.y * w20r[4 * o4 + 1] + vr.y * w21r[4 * o4 + 1];
                a2r += vr.z * w20r[4 * o4 + 2] - vi.z * w21r[4 * o4 + 2];
                a2i += vi.z * w20r[4 * o4 + 2] + vr.z * w21r[4 * o4 + 2];
                a2r += vr.w * w20r[4 * o4 + 3] - vi.w * w21r[4 * o4 + 3];
                a2i += vi.w * w20r[4 * o4 + 3] + vr.w * w21r[4 * o4 + 3];
            }
            // softshrink
            a2r = (a2r > LAM) ? (a2r - LAM) : ((a2r < -LAM) ? (a2r + LAM) : 0.f);
            a2i = (a2i > LAM) ? (a2i - LAM) : ((a2i < -LAM) ? (a2i + LAM) : 0.f);

            // inverse ortho DFT, row t only: Re( Y[p] * e^{+2*pi*i*p*t/P} ) / sqrt(P)
            int m2 = (p * t) & pmask;
            float sn2, cs2;
            __sincosf(angStep * (float)m2, &sn2, &cs2);
            float term = (a2r * cs2 - a2i * sn2) * invSqrtP;
            part[pl * 32 + li] = term;
            __syncthreads();

            if (tid < 32) {
                float ssum = 0.f;
                #pragma unroll
                for (int q = 0; q < 8; ++q) ssum += part[q * 32 + tid];
                atomicAdd(&out[(b * T_DIM + t) * C_DIM + n * BS + tid], ssum);
            }
            __syncthreads();
        }
    }
}

extern "C" void kernel_launch(void* const* d_in, const int* in_sizes, int n_in,
                              void* d_out, int out_size, void* d_ws, size_t ws_size,
                              hipStream_t stream) {
    const float* x  = (const float*)d_in[0];
    const float* w1 = (const float*)d_in[1];
    const float* b1 = (const float*)d_in[2];
    const float* w2 = (const float*)d_in[3];
    const float* b2 = (const float*)d_in[4];
    float* out = (float*)d_out;

    int ntot = B_DIM * T_DIM * C_DIM;
    hipLaunchKernelGGL(afno_init, dim3((ntot + 255) / 256), dim3(256), 0, stream,
                       x, out, ntot);
    hipLaunchKernelGGL(afno_main, dim3(4064), dim3(256), 0, stream,
                       x, w1, b1, w2, b2, out);
}

// Round 3
// 305.824 us; speedup vs baseline: 2.4037x; 2.4037x over previous
//
#include <hip/hip_runtime.h>
#include <math.h>

#define LAM 0.01f

typedef _Float16 half2v __attribute__((ext_vector_type(2)));
typedef _Float16 half8v __attribute__((ext_vector_type(8)));

__global__ void afno_init(const float* __restrict__ x, float* __restrict__ out, int n) {
    int i = blockIdx.x * blockDim.x + threadIdx.x;
    if (i < n) out[i] = x[i];
}

#if defined(__has_builtin)
#if __has_builtin(__builtin_amdgcn_fdot2)
#define HAVE_FDOT2 1
#endif
#endif

__device__ __forceinline__ float fdot2(half2v a, half2v b, float c) {
#ifdef HAVE_FDOT2
    return __builtin_amdgcn_fdot2(a, b, c, false);
#else
    return c + (float)a[0] * (float)b[0] + (float)a[1] * (float)b[1];
#endif
}

// One workgroup per (group g, batch b, block n, chunk of 8 frequencies).
// 32-lane group = one frequency p; lane-in-group li = channel in block.
// All matvec communication is in-wave (LDS write + broadcast read, no
// __syncthreads); cross-frequency reduction is shfl_xor + atomicAdd.
__global__ __launch_bounds__(256, 4)
void afno_main(const float* __restrict__ x,
               const float* __restrict__ w1,
               const float* __restrict__ b1,
               const float* __restrict__ w2,
               const float* __restrict__ b2,
               float* __restrict__ out) {
    const int gP[7]  = {8, 16, 32, 64, 128, 256, 512};
    const int gT0[7] = {0, 7, 15, 31, 63, 127, 255};
    const int gT1[7] = {6, 14, 30, 62, 126, 254, 255};
    const int gOff[8] = {0, 32, 96, 224, 480, 992, 2016, 4064};

    int bid = blockIdx.x;
    int g = 0;
    #pragma unroll
    for (int k = 1; k < 7; ++k) if (bid >= gOff[k]) g = k;
    int r = bid - gOff[g];
    int chunk = r >> 5;
    int bn    = r & 31;
    int b = bn >> 3;
    int n = bn & 7;
    int P  = gP[g];
    int t0 = gT0[g];
    int t1 = gT1[g];
    int pmask = P - 1;
    float invSqrtP = rsqrtf((float)P);

    int tid = threadIdx.x;
    int pl = tid >> 5;
    int li = tid & 31;
    int p  = chunk * 8 + pl;

    __shared__ float xs[256 * 32];       // 32 KB
    __shared__ float2 tw[512];           // 4 KB
    __shared__ _Float16 Xre_h[8 * 32];   // 512 B each
    __shared__ _Float16 Xim_h[8 * 32];
    __shared__ _Float16 o1r_h[8 * 32];
    __shared__ _Float16 o1i_h[8 * 32];

    for (int idx = tid; idx < (t1 + 1) * 32; idx += 256) {
        int s = idx >> 5, i = idx & 31;
        xs[idx] = x[(b * 256 + s) * 256 + n * 32 + i];
    }
    for (int m = tid; m < P; m += 256) {
        float sv, cv;
        sincosf(6.28318530717958647692f * (float)m / (float)P, &sv, &cv);
        tw[m] = make_float2(cv, sv);
    }

    // weights packed as half2 (channel pairs), 64 VGPRs total
    half2v pw10[16], pw11[16], pw20[16], pw21[16];
    #pragma unroll
    for (int k = 0; k < 16; ++k) {
        pw10[k] = half2v{(_Float16)w1[((0 * 8 + n) * 32 + 2 * k) * 32 + li],
                         (_Float16)w1[((0 * 8 + n) * 32 + 2 * k + 1) * 32 + li]};
        pw11[k] = half2v{(_Float16)w1[((1 * 8 + n) * 32 + 2 * k) * 32 + li],
                         (_Float16)w1[((1 * 8 + n) * 32 + 2 * k + 1) * 32 + li]};
        pw20[k] = half2v{(_Float16)w2[((0 * 8 + n) * 32 + 2 * k) * 32 + li],
                         (_Float16)w2[((0 * 8 + n) * 32 + 2 * k + 1) * 32 + li]};
        pw21[k] = half2v{(_Float16)w2[((1 * 8 + n) * 32 + 2 * k) * 32 + li],
                         (_Float16)w2[((1 * 8 + n) * 32 + 2 * k + 1) * 32 + li]};
    }
    float b1r_ = b1[(0 * 8 + n) * 32 + li];
    float b1i_ = b1[(1 * 8 + n) * 32 + li];
    float b2r_ = b2[(0 * 8 + n) * 32 + li];
    float b2i_ = b2[(1 * 8 + n) * 32 + li];

    __syncthreads();   // the only block barrier: xs + tw ready

    const half8v* Xre8 = (const half8v*)(Xre_h + pl * 32);
    const half8v* Xim8 = (const half8v*)(Xim_h + pl * 32);
    const half8v* o1r8 = (const half8v*)(o1r_h + pl * 32);
    const half8v* o1i8 = (const half8v*)(o1i_h + pl * 32);

    float Xre = 0.f, Xim = 0.f;
    int m = 0;   // (p*s) mod P, walked incrementally

    for (int s = 0; s <= t1; ++s) {
        float2 w = tw[m];                 // broadcast per 32-group
        float xv = xs[s * 32 + li];
        Xre = fmaf(xv, w.x, Xre);
        Xim = fmaf(xv, -w.y, Xim);

        if (s >= t0) {
            Xre_h[pl * 32 + li] = (_Float16)(Xre * invSqrtP);
            Xim_h[pl * 32 + li] = (_Float16)(Xim * invSqrtP);
            asm volatile("s_waitcnt lgkmcnt(0)" ::: "memory");
            __builtin_amdgcn_sched_barrier(0);

            float r1 = 0.f, r2 = 0.f, r3 = 0.f, r4 = 0.f;
            #pragma unroll
            for (int q = 0; q < 4; ++q) {
                half8v vr = Xre8[q];
                half8v vi = Xim8[q];
                #pragma unroll
                for (int j = 0; j < 4; ++j) {
                    half2v hr = {vr[2 * j], vr[2 * j + 1]};
                    half2v hi = {vi[2 * j], vi[2 * j + 1]};
                    r1 = fdot2(hr, pw10[4 * q + j], r1);
                    r2 = fdot2(hi, pw11[4 * q + j], r2);
                    r3 = fdot2(hi, pw10[4 * q + j], r3);
                    r4 = fdot2(hr, pw11[4 * q + j], r4);
                }
            }
            float a1r = fmaxf(b1r_ + r1 - r2, 0.f);
            float a1i = fmaxf(b1i_ + r3 + r4, 0.f);

            o1r_h[pl * 32 + li] = (_Float16)a1r;
            o1i_h[pl * 32 + li] = (_Float16)a1i;
            asm volatile("s_waitcnt lgkmcnt(0)" ::: "memory");
            __builtin_amdgcn_sched_barrier(0);

            r1 = 0.f; r2 = 0.f; r3 = 0.f; r4 = 0.f;
            #pragma unroll
            for (int q = 0; q < 4; ++q) {
                half8v vr = o1r8[q];
                half8v vi = o1i8[q];
                #pragma unroll
                for (int j = 0; j < 4; ++j) {
                    half2v hr = {vr[2 * j], vr[2 * j + 1]};
                    half2v hi = {vi[2 * j], vi[2 * j + 1]};
                    r1 = fdot2(hr, pw20[4 * q + j], r1);
                    r2 = fdot2(hi, pw21[4 * q + j], r2);
                    r3 = fdot2(hi, pw20[4 * q + j], r3);
                    r4 = fdot2(hr, pw21[4 * q + j], r4);
                }
            }
            float a2r = b2r_ + r1 - r2;
            float a2i = b2i_ + r3 + r4;
            a2r = (a2r > LAM) ? (a2r - LAM) : ((a2r < -LAM) ? (a2r + LAM) : 0.f);
            a2i = (a2i > LAM) ? (a2i - LAM) : ((a2i < -LAM) ? (a2i + LAM) : 0.f);

            // inverse twiddle at t=s is the same table entry: e^{+2pi i m/P}
            float term = (a2r * w.x - a2i * w.y) * invSqrtP;
            term += __shfl_xor(term, 32, 64);
            if ((tid & 32) == 0)
                atomicAdd(&out[(b * 256 + s) * 256 + n * 32 + li], term);
        }
        m = (m + p) & pmask;
    }
}

extern "C" void kernel_launch(void* const* d_in, const int* in_sizes, int n_in,
                              void* d_out, int out_size, void* d_ws, size_t ws_size,
                              hipStream_t stream) {
    const float* x  = (const float*)d_in[0];
    const float* w1 = (const float*)d_in[1];
    const float* b1 = (const float*)d_in[2];
    const float* w2 = (const float*)d_in[3];
    const float* b2 = (const float*)d_in[4];
    float* out = (float*)d_out;

    int ntot = 4 * 256 * 256;
    hipLaunchKernelGGL(afno_init, dim3((ntot + 255) / 256), dim3(256), 0, stream,
                       x, out, ntot);
    hipLaunchKernelGGL(afno_main, dim3(4064), dim3(256), 0, stream,
                       x, w1, b1, w2, b2, out);
}

// Round 5
// 125.289 us; speedup vs baseline: 5.8673x; 2.4409x over previous
//
#include <hip/hip_runtime.h>
#include <math.h>

#define LAM 0.01f

typedef __bf16 bf16x8 __attribute__((ext_vector_type(8)));
typedef float f32x4 __attribute__((ext_vector_type(4)));
typedef short short8v __attribute__((ext_vector_type(8)));

#define BF(v) __builtin_bit_cast(bf16x8, (v))

__global__ void afno_init(const float* __restrict__ x, float* __restrict__ out, int n) {
    int i = blockIdx.x * blockDim.x + threadIdx.x;
    if (i < n) out[i] = x[i];
}

__device__ __forceinline__ unsigned short f2bf(float f) {
    __bf16 h = (__bf16)f;
    return __builtin_bit_cast(unsigned short, h);
}

// One block = (group g, b, n, quad-of-16-freq-chunks); 4 waves = 4 chunks.
// Wave layout (mfma_f32_16x16x32_bf16):
//   A (X state, registers): row(freq) = lane&15, k(channel) = (lane>>4)*8 + j
//   B (weights):            k = (lane>>4)*8 + j, col = h*16 + (lane&15)
//   C/D:                    col = lane&15, row = (lane>>4)*4 + reg   [m89-verified]
__global__ __launch_bounds__(256, 2)
void afno_mfma(const float* __restrict__ x,
               const float* __restrict__ w1,
               const float* __restrict__ b1,
               const float* __restrict__ w2,
               const float* __restrict__ b2,
               float* __restrict__ out) {
    __shared__ float xs[256 * 32];          // 32 KB, prescaled by 1/sqrt(P)
    __shared__ float2 tw[512];              // 4 KB  (cos, sin) of +2*pi*m/P
    __shared__ unsigned short tbuf[4 * 2 * 640];  // per-wave R/I [16][40] bf16, 10 KB

    int bid = blockIdx.x;
    int g, local;
    if (bid < 128)      { g = 5; local = bid; }        // P=256 (critical path first)
    else if (bid < 192) { g = 4; local = bid - 128; }  // P=128
    else if (bid < 448) { g = 6; local = bid - 192; }  // P=512
    else if (bid < 480) { g = 3; local = bid - 448; }  // P=64
    else if (bid < 512) { g = 2; local = bid - 480; }  // P=32
    else if (bid < 544) { g = 1; local = bid - 512; }  // P=16
    else                { g = 0; local = bid - 544; }  // P=8
    const int gT0[7] = {0, 7, 15, 31, 63, 127, 255};
    const int gT1[7] = {6, 14, 30, 62, 126, 254, 255};
    int P = 8 << g;
    int t0 = gT0[g], t1 = gT1[g];
    int pmask = P - 1;
    int bn = local & 31, quad = local >> 5;
    int b = bn >> 3, n = bn & 7;
    float invSqrtP = rsqrtf((float)P);

    int tid = threadIdx.x;
    int wv = tid >> 6;
    int lane = tid & 63;
    int lg = lane >> 4;
    int l15 = lane & 15;
    int krow = lg * 8;

    // ---- stage xs (prescaled) + twiddle table ----
    int rows = t1 + 1;
    for (int idx = tid; idx < rows * 32; idx += 256) {
        int s = idx >> 5, i = idx & 31;
        xs[idx] = x[(b * 256 + s) * 256 + n * 32 + i] * invSqrtP;
    }
    for (int mm = tid; mm < P; mm += 256) {
        float sv, cv;
        sincosf(6.28318530717958647692f * (float)mm / (float)P, &sv, &cv);
        tw[mm] = make_float2(cv, sv);
    }

    // ---- weights -> bf16 B-fragments (per lane) ----
    const float* w1r = w1 + (0 * 8 + n) * 1024;
    const float* w1i = w1 + (1 * 8 + n) * 1024;
    const float* w2r = w2 + (0 * 8 + n) * 1024;
    const float* w2i = w2 + (1 * 8 + n) * 1024;
    short8v W10s[2], W11s[2], W20s[2], W21s[2];
    float b1rv[2], b1iv[2], b2rv[2], b2iv[2];
    #pragma unroll
    for (int h = 0; h < 2; ++h) {
        int col = h * 16 + l15;
        #pragma unroll
        for (int j = 0; j < 8; ++j) {
            W10s[h][j] = (short)f2bf(w1r[(krow + j) * 32 + col]);
            W11s[h][j] = (short)f2bf(w1i[(krow + j) * 32 + col]);
            W20s[h][j] = (short)f2bf(w2r[(krow + j) * 32 + col]);
            W21s[h][j] = (short)f2bf(w2i[(krow + j) * 32 + col]);
        }
        b1rv[h] = b1[(0 * 8 + n) * 32 + col];
        b1iv[h] = b1[(1 * 8 + n) * 32 + col];
        b2rv[h] = b2[(0 * 8 + n) * 32 + col];
        b2iv[h] = b2[(1 * 8 + n) * 32 + col];
    }
    __syncthreads();   // only block barrier

    int chunks16 = (P >= 16) ? (P >> 4) : 1;
    int c16 = quad * 4 + wv;
    if (c16 >= chunks16) return;   // idle waves: no further barriers exist

    int cbase = c16 * 16;
    int pA = cbase + l15;          // this lane's A-row frequency
    int prow0 = cbase + lg * 4;    // C-row base frequency (+r)

    float Xre[8] = {0.f, 0.f, 0.f, 0.f, 0.f, 0.f, 0.f, 0.f};
    float Xim[8] = {0.f, 0.f, 0.f, 0.f, 0.f, 0.f, 0.f, 0.f};
    int mA = 0;
    int mrow[4];
    #pragma unroll
    for (int r = 0; r < 4; ++r) mrow[r] = ((prow0 + r) * t0) & pmask;

    unsigned short* bufR = tbuf + wv * 1280;
    unsigned short* bufI = bufR + 640;
    unsigned short* wpR = bufR + (lg * 4) * 40 + l15;     // + r*40 + h*16
    unsigned short* wpI = bufI + (lg * 4) * 40 + l15;
    const short8v* rpR = (const short8v*)(bufR + l15 * 40 + krow);  // 16B aligned
    const short8v* rpI = (const short8v*)(bufI + l15 * 40 + krow);

    const f32x4 zf = {0.f, 0.f, 0.f, 0.f};

    for (int s = 0; s <= t1; ++s) {
        // incremental prefix DFT: X[p] += e^{-2pi i p s/P} * x[s]  (xs prescaled)
        float4 xv0 = *(const float4*)(xs + s * 32 + krow);
        float4 xv1 = *(const float4*)(xs + s * 32 + krow + 4);
        float2 tA = tw[mA];
        mA = (mA + pA) & pmask;
        float xvv[8] = {xv0.x, xv0.y, xv0.z, xv0.w, xv1.x, xv1.y, xv1.z, xv1.w};
        #pragma unroll
        for (int j = 0; j < 8; ++j) {
            Xre[j] = fmaf(xvv[j], tA.x, Xre[j]);
            Xim[j] = fmaf(xvv[j], -tA.y, Xim[j]);
        }
        if (s < t0) continue;

        // ---- A-fragments (bf16), plus sign-flipped Im for the -Xi*W11 term ----
        short8v ars, ais, ains;
        #pragma unroll
        for (int j = 0; j < 8; ++j) {
            ars[j] = (short)f2bf(Xre[j]);
            ais[j] = (short)f2bf(Xim[j]);
            ains[j] = ais[j] ^ (short)0x8000;
        }
        bf16x8 ar = BF(ars), ai = BF(ais), ain = BF(ains);

        // ---- layer 1: o1r = Xr*W10 - Xi*W11, o1i = Xi*W10 + Xr*W11 ----
        f32x4 o1r[2], o1i[2];
        #pragma unroll
        for (int h = 0; h < 2; ++h) {
            o1r[h] = __builtin_amdgcn_mfma_f32_16x16x32_bf16(ar,  BF(W10s[h]), zf, 0, 0, 0);
            o1r[h] = __builtin_amdgcn_mfma_f32_16x16x32_bf16(ain, BF(W11s[h]), o1r[h], 0, 0, 0);
            o1i[h] = __builtin_amdgcn_mfma_f32_16x16x32_bf16(ai,  BF(W10s[h]), zf, 0, 0, 0);
            o1i[h] = __builtin_amdgcn_mfma_f32_16x16x32_bf16(ar,  BF(W11s[h]), o1i[h], 0, 0, 0);
        }
        // bias + relu, C-layout -> A-layout transpose through padded LDS
        #pragma unroll
        for (int h = 0; h < 2; ++h) {
            #pragma unroll
            for (int r = 0; r < 4; ++r) {
                float vr_ = fmaxf(o1r[h][r] + b1rv[h], 0.f);
                float vi_ = fmaxf(o1i[h][r] + b1iv[h], 0.f);
                wpR[r * 40 + h * 16] = f2bf(vr_);
                wpI[r * 40 + h * 16] = f2bf(vi_);
            }
        }
        asm volatile("s_waitcnt lgkmcnt(0)" ::: "memory");
        __builtin_amdgcn_sched_barrier(0);
        short8v a2rs = *rpR;
        short8v a2is = *rpI;
        short8v a2ins;
        #pragma unroll
        for (int j = 0; j < 8; ++j) a2ins[j] = a2is[j] ^ (short)0x8000;
        bf16x8 a2r = BF(a2rs), a2i = BF(a2is), a2in = BF(a2ins);

        // ---- layer 2: o2r = o1r*W20 - o1i*W21, o2i = o1i*W20 + o1r*W21 ----
        f32x4 o2r[2], o2i[2];
        #pragma unroll
        for (int h = 0; h < 2; ++h) {
            o2r[h] = __builtin_amdgcn_mfma_f32_16x16x32_bf16(a2r,  BF(W20s[h]), zf, 0, 0, 0);
            o2r[h] = __builtin_amdgcn_mfma_f32_16x16x32_bf16(a2in, BF(W21s[h]), o2r[h], 0, 0, 0);
            o2i[h] = __builtin_amdgcn_mfma_f32_16x16x32_bf16(a2i,  BF(W20s[h]), zf, 0, 0, 0);
            o2i[h] = __builtin_amdgcn_mfma_f32_16x16x32_bf16(a2r,  BF(W21s[h]), o2i[h], 0, 0, 0);
        }

        // ---- bias, softshrink, inverse twiddle at row t=s, reduce over rows ----
        float sh0 = 0.f, sh1 = 0.f;
        #pragma unroll
        for (int r = 0; r < 4; ++r) {
            float2 tR = tw[mrow[r]];
            mrow[r] = (mrow[r] + prow0 + r) & pmask;
            {
                float vr_ = o2r[0][r] + b2rv[0];
                vr_ -= __builtin_amdgcn_fmed3f(vr_, -LAM, LAM);   // softshrink
                float vi_ = o2i[0][r] + b2iv[0];
                vi_ -= __builtin_amdgcn_fmed3f(vi_, -LAM, LAM);
                sh0 += vr_ * tR.x - vi_ * tR.y;
            }
            {
                float vr_ = o2r[1][r] + b2rv[1];
                vr_ -= __builtin_amdgcn_fmed3f(vr_, -LAM, LAM);
                float vi_ = o2i[1][r] + b2iv[1];
                vi_ -= __builtin_amdgcn_fmed3f(vi_, -LAM, LAM);
                sh1 += vr_ * tR.x - vi_ * tR.y;
            }
        }
        sh0 += __shfl_xor(sh0, 16);
        sh1 += __shfl_xor(sh1, 16);
        if (P > 8) {           // P=8: rows 8..15 alias freqs 0..7 -> exclude
            sh0 += __shfl_xor(sh0, 32);
            sh1 += __shfl_xor(sh1, 32);
        }
        float vsel = (lane & 16) ? sh1 : sh0;
        if (lane < 32)
            atomicAdd(out + (b * 256 + s) * 256 + n * 32 + (lane & 31), vsel * invSqrtP);
    }
}

extern "C" void kernel_launch(void* const* d_in, const int* in_sizes, int n_in,
                              void* d_out, int out_size, void* d_ws, size_t ws_size,
                              hipStream_t stream) {
    const float* x  = (const float*)d_in[0];
    const float* w1 = (const float*)d_in[1];
    const float* b1 = (const float*)d_in[2];
    const float* w2 = (const float*)d_in[3];
    const float* b2 = (const float*)d_in[4];
    float* out = (float*)d_out;

    int ntot = 4 * 256 * 256;
    hipLaunchKernelGGL(afno_init, dim3((ntot + 255) / 256), dim3(256), 0, stream,
                       x, out, ntot);
    hipLaunchKernelGGL(afno_mfma, dim3(576), dim3(256), 0, stream,
                       x, w1, b1, w2, b2, out);
}

// Round 6
// 78.310 us; speedup vs baseline: 9.3871x; 1.5999x over previous
//
#include <hip/hip_runtime.h>
#include <math.h>
#include <type_traits>

#define LAM 0.01f

typedef __bf16 bf16x8 __attribute__((ext_vector_type(8)));
typedef float f32x4 __attribute__((ext_vector_type(4)));
typedef short short8v __attribute__((ext_vector_type(8)));

#define BF(v) __builtin_bit_cast(bf16x8, (v))
#define MFMA __builtin_amdgcn_mfma_f32_16x16x32_bf16

__global__ void afno_init(const float* __restrict__ x, float* __restrict__ out, int n) {
    int i = blockIdx.x * blockDim.x + threadIdx.x;
    if (i < n) out[i] = x[i];
}

__device__ __forceinline__ unsigned short f2bf(float f) {
    __bf16 h = (__bf16)f;
    return __builtin_bit_cast(unsigned short, h);
}
__device__ __forceinline__ float bf2f(unsigned short u) {
    unsigned int v = ((unsigned int)u) << 16;
    return __builtin_bit_cast(float, v);
}

// wave task id tau in [0,120): P, chunk-of-16-freqs, t-segment, jump target.
// sh = 9 - log2(P); all twiddle indices live in 512-space (angle 2*pi*m/512).
struct Task { int sh, c16, t_lo, t_hi, jump_s; };
__device__ __forceinline__ Task task_params(int tau) {
    Task tk;
    if (tau < 64)        { int seg = tau >> 4; tk.sh = 1; tk.c16 = tau & 15;
                           tk.t_lo = 127 + 32 * seg; tk.t_hi = tk.t_lo + 31; tk.jump_s = tk.t_lo + 1; }  // P=256
    else if (tau < 96)   { tk.sh = 0; tk.c16 = tau - 64; tk.t_lo = 255; tk.t_hi = 255; tk.jump_s = 256; } // P=512
    else if (tau < 112)  { int u = tau - 96; int seg = u >> 3; tk.sh = 2; tk.c16 = u & 7;
                           tk.t_lo = 63 + 32 * seg; tk.t_hi = tk.t_lo + 31; tk.jump_s = tk.t_lo + 1; }    // P=128
    else if (tau < 116)  { tk.sh = 3; tk.c16 = tau - 112; tk.t_lo = 31; tk.t_hi = 62; tk.jump_s = 32; }   // P=64
    else if (tau < 118)  { tk.sh = 4; tk.c16 = tau - 116; tk.t_lo = 15; tk.t_hi = 30; tk.jump_s = 0; }    // P=32
    else if (tau == 118) { tk.sh = 5; tk.c16 = 0; tk.t_lo = 7; tk.t_hi = 14; tk.jump_s = 0; }             // P=16
    else                 { tk.sh = 6; tk.c16 = 0; tk.t_lo = 0; tk.t_hi = 6;  tk.jump_s = 0; }             // P=8
    return tk;
}

// MFMA layouts (m89-verified convention):
//  A: row = lane&15, k = (lane>>4)*8 + j  |  B: k = (lane>>4)*8 + j, col = lane&15
//  C/D: col = lane&15, row = (lane>>4)*4 + reg
__global__ __launch_bounds__(256, 2)
void afno_mfma(const float* __restrict__ x,
               const float* __restrict__ w1,
               const float* __restrict__ b1,
               const float* __restrict__ w2,
               const float* __restrict__ b2,
               float* __restrict__ out) {
    __shared__ unsigned short xs[8192];     // raw bf16 x, [rows<=256][32]        16 KB
    __shared__ float2 tw[544];              // padded twiddles (idx m + (m>>4))   4.25 KB
    __shared__ unsigned short tbuf[20480];  // per-wave scratch, 4 x 10240 B      40 KB

    int bid = blockIdx.x;
    int w  = bid >> 5;          // 0..29 task-slot (heavy slots dispatched first)
    int bn = bid & 31;
    int b = bn >> 3, n = bn & 7;

    int tid = threadIdx.x;
    int wv = tid >> 6;
    int lane = tid & 63;
    int lg = lane >> 4;
    int l15 = lane & 15;
    int krow = lg * 8;

    // ---- stage x rows (raw bf16) ----
    int rows = 0;
    #pragma unroll
    for (int q = 0; q < 4; ++q) {
        Task t2 = task_params((w << 2) | q);
        rows = max(rows, t2.t_hi + 1);
    }
    for (int idx = tid; idx < rows * 16; idx += 256) {
        int row = idx >> 4, cp = idx & 15;
        float2 v = *(const float2*)(x + (b * 256 + row) * 256 + n * 32 + cp * 2);
        unsigned int pk = (unsigned int)f2bf(v.x) | ((unsigned int)f2bf(v.y) << 16);
        *(unsigned int*)(xs + idx * 2) = pk;
    }
    for (int m = tid; m < 512; m += 256) {
        float sv, cv;
        sincosf(6.28318530717958647692f * (float)m * (1.0f / 512.0f), &sv, &cv);
        tw[m + (m >> 4)] = make_float2(cv, sv);
    }

    // ---- weights -> bf16 B-fragments ----
    const float* w1r = w1 + n * 1024;
    const float* w1i = w1 + (8 + n) * 1024;
    const float* w2r = w2 + n * 1024;
    const float* w2i = w2 + (8 + n) * 1024;
    short8v W10[2], W11[2], W20[2], W21[2];
    float b1r_[2], b1i_[2], b2r_[2], b2i_[2];
    #pragma unroll
    for (int h = 0; h < 2; ++h) {
        int col = h * 16 + l15;
        #pragma unroll
        for (int j = 0; j < 8; ++j) {
            W10[h][j] = (short)f2bf(w1r[(krow + j) * 32 + col]);
            W11[h][j] = (short)f2bf(w1i[(krow + j) * 32 + col]);
            W20[h][j] = (short)f2bf(w2r[(krow + j) * 32 + col]);
            W21[h][j] = (short)f2bf(w2i[(krow + j) * 32 + col]);
        }
        b1r_[h] = b1[n * 32 + col];
        b1i_[h] = b1[(8 + n) * 32 + col];
        b2r_[h] = b2[n * 32 + col];
        b2i_[h] = b2[(8 + n) * 32 + col];
    }
    __syncthreads();   // only block barrier

    Task tk = task_params((w << 2) | wv);
    int P = 512 >> tk.sh;
    float invSqrtP = rsqrtf((float)P);
    int cbase = tk.c16 * 16;
    int pA5 = (cbase + l15) << tk.sh;
    int prow5[4];
    #pragma unroll
    for (int r = 0; r < 4; ++r) prow5[r] = (cbase + lg * 4 + r) << tk.sh;

    unsigned short* wslab = tbuf + wv * 5120;

    float Xre[8] = {0,0,0,0,0,0,0,0}, Xim[8] = {0,0,0,0,0,0,0,0};
    int mA5 = 0;
    bool jumped = tk.jump_s > 0;

    if (jumped) {
        // ---- prefix jump: X = sum_{s<jump_s} e^{-i th} x[s] via MFMA ----
        f32x4 jre0 = {0,0,0,0}, jre1 = {0,0,0,0}, jim0 = {0,0,0,0}, jim1 = {0,0,0,0};
        int nkk = tk.jump_s >> 5;
        for (int kk = 0; kk < nkk; ++kk) {
            int sb = kk * 32;
            int mj = (pA5 * (sb + krow)) & 511;
            short8v ac, an_;
            #pragma unroll
            for (int j = 0; j < 8; ++j) {
                float2 t = tw[mj + (mj >> 4)];
                mj = (mj + pA5) & 511;
                ac[j]  = (short)f2bf(t.x);
                an_[j] = (short)f2bf(-t.y);
            }
            short8v bx0, bx1;
            #pragma unroll
            for (int j = 0; j < 8; ++j) {
                int base = (sb + krow + j) * 32 + l15;
                bx0[j] = (short)xs[base];
                bx1[j] = (short)xs[base + 16];
            }
            jre0 = MFMA(BF(ac),  BF(bx0), jre0, 0, 0, 0);
            jim0 = MFMA(BF(an_), BF(bx0), jim0, 0, 0, 0);
            jre1 = MFMA(BF(ac),  BF(bx1), jre1, 0, 0, 0);
            jim1 = MFMA(BF(an_), BF(bx1), jim1, 0, 0, 0);
        }
        // C-layout -> A-layout transpose (f32, padded stride 33)
        float* jt = (float*)wslab;
        #pragma unroll
        for (int r = 0; r < 4; ++r) {
            jt[(lg * 4 + r) * 33 + l15]            = jre0[r];
            jt[(lg * 4 + r) * 33 + 16 + l15]       = jre1[r];
            jt[528 + (lg * 4 + r) * 33 + l15]      = jim0[r];
            jt[528 + (lg * 4 + r) * 33 + 16 + l15] = jim1[r];
        }
        asm volatile("s_waitcnt lgkmcnt(0)" ::: "memory");
        __builtin_amdgcn_sched_barrier(0);
        #pragma unroll
        for (int j = 0; j < 8; ++j) {
            Xre[j] = jt[l15 * 33 + krow + j] * invSqrtP;
            Xim[j] = jt[528 + l15 * 33 + krow + j] * invSqrtP;
        }
        asm volatile("s_waitcnt lgkmcnt(0)" ::: "memory");
        __builtin_amdgcn_sched_barrier(0);
        mA5 = (pA5 * tk.jump_s) & 511;
    } else {
        // small-P incremental prefix (<=15 steps)
        for (int s = 0; s < tk.t_lo; ++s) {
            int mi = mA5 + (mA5 >> 4);
            float2 tA = tw[mi];
            mA5 = (mA5 + pA5) & 511;
            short8v xv8 = *(const short8v*)(xs + s * 32 + krow);
            #pragma unroll
            for (int j = 0; j < 8; ++j) {
                float xf = bf2f((unsigned short)xv8[j]) * invSqrtP;
                Xre[j] = fmaf(xf, tA.x, Xre[j]);
                Xim[j] = fmaf(xf, -tA.y, Xim[j]);
            }
        }
    }

    int mrow5[4];
    #pragma unroll
    for (int r = 0; r < 4; ++r) mrow5[r] = (prow5[r] * tk.t_lo) & 511;

    auto run_steps = [&](int s0, auto NQC, bool upd_first) {
        constexpr int NQ = decltype(NQC)::value;
        short8v ar[NQ], av[NQ], an_[NQ];
        #pragma unroll
        for (int q = 0; q < NQ; ++q) {
            if (upd_first || q > 0) {
                int mi = mA5 + (mA5 >> 4);
                float2 tA = tw[mi];
                mA5 = (mA5 + pA5) & 511;
                short8v xv8 = *(const short8v*)(xs + (s0 + q) * 32 + krow);
                #pragma unroll
                for (int j = 0; j < 8; ++j) {
                    float xf = bf2f((unsigned short)xv8[j]) * invSqrtP;
                    Xre[j] = fmaf(xf, tA.x, Xre[j]);
                    Xim[j] = fmaf(xf, -tA.y, Xim[j]);
                }
            }
            #pragma unroll
            for (int j = 0; j < 8; ++j) {
                ar[q][j]  = (short)f2bf(Xre[j]);
                av[q][j]  = (short)f2bf(Xim[j]);
                an_[q][j] = av[q][j] ^ (short)0x8000;
            }
        }
        // layer 1 (bias in accumulator init)
        f32x4 o1r[NQ][2], o1i[NQ][2];
        #pragma unroll
        for (int q = 0; q < NQ; ++q) {
            #pragma unroll
            for (int h = 0; h < 2; ++h) {
                f32x4 cr = {b1r_[h], b1r_[h], b1r_[h], b1r_[h]};
                f32x4 ci = {b1i_[h], b1i_[h], b1i_[h], b1i_[h]};
                o1r[q][h] = MFMA(BF(ar[q]),  BF(W10[h]), cr, 0, 0, 0);
                o1r[q][h] = MFMA(BF(an_[q]), BF(W11[h]), o1r[q][h], 0, 0, 0);
                o1i[q][h] = MFMA(BF(av[q]),  BF(W10[h]), ci, 0, 0, 0);
                o1i[q][h] = MFMA(BF(ar[q]),  BF(W11[h]), o1i[q][h], 0, 0, 0);
            }
        }
        // relu + C->A transpose through per-wave LDS
        #pragma unroll
        for (int q = 0; q < NQ; ++q) {
            unsigned short* wR = wslab + q * 1280 + lg * 160 + l15;
            #pragma unroll
            for (int h = 0; h < 2; ++h) {
                #pragma unroll
                for (int r = 0; r < 4; ++r) {
                    wR[r * 40 + h * 16]       = f2bf(fmaxf(o1r[q][h][r], 0.f));
                    wR[640 + r * 40 + h * 16] = f2bf(fmaxf(o1i[q][h][r], 0.f));
                }
            }
        }
        asm volatile("s_waitcnt lgkmcnt(0)" ::: "memory");
        __builtin_amdgcn_sched_barrier(0);
        short8v a2r[NQ], a2i[NQ], a2n[NQ];
        #pragma unroll
        for (int q = 0; q < NQ; ++q) {
            a2r[q] = *(const short8v*)(wslab + q * 1280 + l15 * 40 + krow);
            a2i[q] = *(const short8v*)(wslab + q * 1280 + 640 + l15 * 40 + krow);
            #pragma unroll
            for (int j = 0; j < 8; ++j) a2n[q][j] = a2i[q][j] ^ (short)0x8000;
        }
        // epilogue twiddles (prefetch)
        float2 trow[NQ][4];
        #pragma unroll
        for (int q = 0; q < NQ; ++q) {
            #pragma unroll
            for (int r = 0; r < 4; ++r) {
                int mi = (mrow5[r] + q * prow5[r]) & 511;
                trow[q][r] = tw[mi + (mi >> 4)];
            }
        }
        // layer 2
        f32x4 o2r[NQ][2], o2i[NQ][2];
        #pragma unroll
        for (int q = 0; q < NQ; ++q) {
            #pragma unroll
            for (int h = 0; h < 2; ++h) {
                f32x4 cr = {b2r_[h], b2r_[h], b2r_[h], b2r_[h]};
                f32x4 ci = {b2i_[h], b2i_[h], b2i_[h], b2i_[h]};
                o2r[q][h] = MFMA(BF(a2r[q]), BF(W20[h]), cr, 0, 0, 0);
                o2r[q][h] = MFMA(BF(a2n[q]), BF(W21[h]), o2r[q][h], 0, 0, 0);
                o2i[q][h] = MFMA(BF(a2i[q]), BF(W20[h]), ci, 0, 0, 0);
                o2i[q][h] = MFMA(BF(a2r[q]), BF(W21[h]), o2i[q][h], 0, 0, 0);
            }
        }
        // softshrink + inverse twiddle + row-reduce + atomic
        #pragma unroll
        for (int q = 0; q < NQ; ++q) {
            float sh0 = 0.f, sh1 = 0.f;
            #pragma unroll
            for (int r = 0; r < 4; ++r) {
                float c_ = trow[q][r].x, s_ = trow[q][r].y;
                float v0r = o2r[q][0][r]; v0r -= __builtin_amdgcn_fmed3f(v0r, -LAM, LAM);
                float v0i = o2i[q][0][r]; v0i -= __builtin_amdgcn_fmed3f(v0i, -LAM, LAM);
                sh0 = fmaf(v0r, c_, sh0); sh0 = fmaf(-v0i, s_, sh0);
                float v1r = o2r[q][1][r]; v1r -= __builtin_amdgcn_fmed3f(v1r, -LAM, LAM);
                float v1i = o2i[q][1][r]; v1i -= __builtin_amdgcn_fmed3f(v1i, -LAM, LAM);
                sh1 = fmaf(v1r, c_, sh1); sh1 = fmaf(-v1i, s_, sh1);
            }
            sh0 += __shfl_xor(sh0, 16);
            sh1 += __shfl_xor(sh1, 16);
            if (P > 8) {             // P=8: rows 8..15 alias freqs 0..7 -> exclude
                sh0 += __shfl_xor(sh0, 32);
                sh1 += __shfl_xor(sh1, 32);
            }
            float vsel = (lane & 16) ? sh1 : sh0;
            if (lane < 32)
                atomicAdd(out + (b * 256 + s0 + q) * 256 + n * 32 + (lane & 31), vsel * invSqrtP);
        }
        #pragma unroll
        for (int r = 0; r < 4; ++r) mrow5[r] = (mrow5[r] + NQ * prow5[r]) & 511;
    };

    int s = tk.t_lo;
    bool first = true;
    while (s + 3 <= tk.t_hi) {
        run_steps(s, std::integral_constant<int, 4>(), !(jumped && first));
        first = false; s += 4;
    }
    while (s <= tk.t_hi) {
        run_steps(s, std::integral_constant<int, 1>(), !(jumped && first));
        first = false; s += 1;
    }
}

extern "C" void kernel_launch(void* const* d_in, const int* in_sizes, int n_in,
                              void* d_out, int out_size, void* d_ws, size_t ws_size,
                              hipStream_t stream) {
    const float* x  = (const float*)d_in[0];
    const float* w1 = (const float*)d_in[1];
    const float* b1 = (const float*)d_in[2];
    const float* w2 = (const float*)d_in[3];
    const float* b2 = (const float*)d_in[4];
    float* out = (float*)d_out;

    int ntot = 4 * 256 * 256;
    hipLaunchKernelGGL(afno_init, dim3((ntot + 255) / 256), dim3(256), 0, stream,
                       x, out, ntot);
    hipLaunchKernelGGL(afno_mfma, dim3(960), dim3(256), 0, stream,
                       x, w1, b1, w2, b2, out);
}